// Round 15
// baseline (600.153 us; speedup 1.0000x reference)
//
#include <hip/hip_runtime.h>
#include <hip/hip_bf16.h>

// Dense transformer forward, round 15:
// (a) attention phase-1 operand-swapped so Q/K/V epilogues are packed uint2
//     LDS stores (48 scalar ds_write_u16 -> 12 ds_write_b64; kills the
//     measured bank-conflict hotspot);
// (b) outproj+LN1+FFN+LN2 merged into one block_kernel (post-LN1 h never
//     touches HBM; residual held in registers; 6 fewer dispatches/launch).
// B=64 x L=512, D=128, H=8 (DH=16), LAYERS=6, FF=512, OUT=10. Mask all-true.

#define NROWS (64 * 512)
#define NLAYER 6

typedef __bf16 bf16x8 __attribute__((ext_vector_type(8)));
typedef float  f32x4  __attribute__((ext_vector_type(4)));
typedef float  f32x16 __attribute__((ext_vector_type(16)));

#define QSCALE 0.36067376022224085f   // 1/sqrt(16) * log2(e)

#if defined(__has_builtin)
#  if __has_builtin(__builtin_amdgcn_exp2f)
#    define FAST_EXP2(x) __builtin_amdgcn_exp2f(x)
#  endif
#endif
#ifndef FAST_EXP2
#  define FAST_EXP2(x) __expf((x) * 0.6931471805599453f)
#endif

__device__ __forceinline__ __hip_bfloat16 f2bf(float x) { return __float2bfloat16(x); }

__device__ __forceinline__ __hip_bfloat16 bf_rta(float a) {
  union { float f; unsigned u; } c{a};
  return __builtin_bit_cast(__hip_bfloat16, (unsigned short)((c.u + 0x8000u) >> 16));
}
__device__ __forceinline__ unsigned pk_rta(float a, float b) {
  union { float f; unsigned u; } ca{a}, cb{b};
  return ((ca.u + 0x8000u) >> 16) | ((cb.u + 0x8000u) & 0xFFFF0000u);
}

// ---------------------------------------------------------------------------
// Merged prep: x conversion + weight conversions/transposes + scaled qkv bias.
// ---------------------------------------------------------------------------
#define PN_X   (NROWS * 128)
#define PN_WP  (128 * 128)
#define PN_QW  (6 * 384 * 128)
#define PN_QB  (6 * 384)
#define PN_OW  (6 * 128 * 128)
#define PN_W1  (6 * 128 * 512)
#define PN_W2  (6 * 512 * 128)
#define PB1 PN_X
#define PB2 (PB1 + PN_WP)
#define PB3 (PB2 + PN_QW)
#define PB4 (PB3 + PN_QB)
#define PB5 (PB4 + PN_OW)
#define PB6 (PB5 + PN_W1)
#define PB7 (PB6 + PN_W2)

__global__ __launch_bounds__(256) void prep_kernel(
    const float* __restrict__ x, __hip_bfloat16* __restrict__ xb,
    const float* __restrict__ Wp, __hip_bfloat16* __restrict__ wp_t,
    const float* __restrict__ qkv_w, __hip_bfloat16* __restrict__ qkvw,
    const float* __restrict__ qkv_b, float* __restrict__ qb_s,
    const float* __restrict__ out_w, __hip_bfloat16* __restrict__ outw,
    const float* __restrict__ ffn_w1, __hip_bfloat16* __restrict__ w1t,
    const float* __restrict__ ffn_w2, __hip_bfloat16* __restrict__ w2t)
{
  const int idx = blockIdx.x * 256 + threadIdx.x;
  if (idx < PB1) {
    xb[idx] = f2bf(x[idx]);
  } else if (idx < PB2) {
    const int i = idx - PB1;
    const int c = i >> 7, r = i & 127;
    wp_t[i] = f2bf(Wp[r * 128 + c]);
  } else if (idx < PB3) {
    const int i = idx - PB2;
    const int row = (i >> 7) % 384;
    qkvw[i] = f2bf(qkv_w[i] * ((row < 128) ? QSCALE : 1.f));
  } else if (idx < PB4) {
    const int i = idx - PB3;
    qb_s[i] = qkv_b[i] * (((i % 384) < 128) ? QSCALE : 1.f);
  } else if (idx < PB5) {
    const int i = idx - PB4;
    outw[i] = f2bf(out_w[i]);
  } else if (idx < PB6) {
    const int i = idx - PB5;                 // [l][c][r], R=128, C=512
    const int l = i >> 16, j = i & 65535;
    const int c = j >> 7, r = j & 127;
    w1t[i] = f2bf(ffn_w1[l * 65536 + r * 512 + c]);
  } else if (idx < PB7) {
    const int i = idx - PB6;                 // [l][c][r], R=512, C=128
    const int l = i >> 16, j = i & 65535;
    const int c = j >> 9, r = j & 511;
    w2t[i] = f2bf(ffn_w2[l * 65536 + r * 128 + c]);
  }
}

// ---------------------------------------------------------------------------
// gemm_fk (R13): used for the input projection only.
// ---------------------------------------------------------------------------
__global__ __launch_bounds__(256) void gemm_fk(
    const __hip_bfloat16* __restrict__ A, const __hip_bfloat16* __restrict__ B,
    const float* __restrict__ bias, __hip_bfloat16* __restrict__ outb,
    int M, int K)
{
  __shared__ __align__(16) __hip_bfloat16 As[64 * 136];
  __shared__ __align__(16) __hip_bfloat16 Bs[128 * 136];

  const int tid = threadIdx.x;
  const int m0 = blockIdx.x << 6;
  const int wave = tid >> 6;
  const int lane = tid & 63;
  const int quad = lane >> 4;
  const int l15 = lane & 15;
  const int wrow = wave * 16;

  f32x4 acc[8];
#pragma unroll
  for (int ni = 0; ni < 8; ++ni) acc[ni] = (f32x4){0.f, 0.f, 0.f, 0.f};

  for (int kc = 0; kc < K; kc += 128) {
#pragma unroll
    for (int p = 0; p < 4; ++p) {
      const int e = tid + (p << 8);
      const int row = e >> 4;
      const int c = e & 15;
      *(uint4*)&As[row * 136 + c * 8] =
          *(const uint4*)(A + (size_t)(m0 + row) * K + kc + c * 8);
    }
#pragma unroll
    for (int p = 0; p < 8; ++p) {
      const int e = tid + (p << 8);
      const int row = e >> 4;
      const int c = e & 15;
      *(uint4*)&Bs[row * 136 + c * 8] =
          *(const uint4*)(B + (size_t)row * K + kc + c * 8);
    }
    __syncthreads();

#pragma unroll
    for (int ks = 0; ks < 4; ++ks) {
      const bf16x8 af = *(const bf16x8*)&As[(wrow + l15) * 136 + ks * 32 + quad * 8];
#pragma unroll
      for (int ni = 0; ni < 8; ++ni) {
        const bf16x8 bfr =
            *(const bf16x8*)&Bs[(ni * 16 + l15) * 136 + ks * 32 + quad * 8];
        acc[ni] = __builtin_amdgcn_mfma_f32_16x16x32_bf16(af, bfr, acc[ni], 0, 0, 0);
      }
    }
    if (kc + 128 < K) __syncthreads();
  }

#pragma unroll
  for (int ni = 0; ni < 8; ++ni) {
    const int cl = ni * 16 + l15;
    const float bv = bias[cl];
#pragma unroll
    for (int r = 0; r < 4; ++r)
      outb[(size_t)(m0 + wrow + quad * 4 + r) * 128 + cl] = bf_rta(acc[ni][r] + bv);
  }
}

// ---------------------------------------------------------------------------
// block_kernel: hb = LN2(hLN1 + relu(hLN1@W1+b1)@W2+b2) where
// hLN1 = LN1(hb + attnb@outw^T + out_b). Post-LN1 h never touches HBM:
// it lives in registers (residual) and the AF LDS tile (FFN A-operand).
// 64 nodes/block (grid 512), 4 waves x 16 nodes. All GEMMs operand-swapped
// (mfma(w, a)) -> D col = node = l15, row = feature = quad*4+r (+ni*16):
// packed uint2 LDS/global IO, LN reductions = in-lane sum + 2 shfl_xor.
// LDS: AF 64x136 (attnb tile -> hLN1 -> F chunks) + Bs 128x136 (outw / W1c /
// W2c) = 52 KB -> 2 blocks/CU.
// ---------------------------------------------------------------------------
__global__ __launch_bounds__(256) void block_kernel(
    const __hip_bfloat16* __restrict__ attnb,
    __hip_bfloat16* __restrict__ hb,
    const __hip_bfloat16* __restrict__ outw,   // [128 n][128 k]
    const float* __restrict__ out_b,
    const float* __restrict__ ln1_g, const float* __restrict__ ln1_b,
    const __hip_bfloat16* __restrict__ w1,     // [512 n][128 k]
    const __hip_bfloat16* __restrict__ w2,     // [128 n][512 k]
    const float* __restrict__ b1, const float* __restrict__ b2,
    const float* __restrict__ ln2_g, const float* __restrict__ ln2_b)
{
  __shared__ __align__(16) __hip_bfloat16 AF[64 * 136];
  __shared__ __align__(16) __hip_bfloat16 Bs[128 * 136];

  const int tid = threadIdx.x;
  const int m0 = blockIdx.x << 6;
  const int wave = tid >> 6;
  const int lane = tid & 63;
  const int quad = lane >> 4;
  const int l15 = lane & 15;
  const int lrow = wave * 16 + l15;            // lane's local node row
  const size_t grow = (size_t)(m0 + lrow);     // global node row

  // ---- stage attnb tile (64x128) + outw (128x128) ----
#pragma unroll
  for (int p = 0; p < 4; ++p) {
    const int e = tid + (p << 8);
    const int row = e >> 4, c = e & 15;
    *(uint4*)&AF[row * 136 + c * 8] =
        *(const uint4*)(attnb + (size_t)(m0 + row) * 128 + c * 8);
  }
#pragma unroll
  for (int p = 0; p < 8; ++p) {
    const int e = tid + (p << 8);
    const int row = e >> 4, c = e & 15;
    *(uint4*)&Bs[row * 136 + c * 8] =
        *(const uint4*)(outw + (size_t)row * 128 + c * 8);
  }
  __syncthreads();

  bf16x8 af[4];
#pragma unroll
  for (int ks = 0; ks < 4; ++ks)
    af[ks] = *(const bf16x8*)&AF[lrow * 136 + ks * 32 + quad * 8];

  // ---- outproj, transposed: acc[ni] row = feat ni*16+quad*4+r, col = node l15
  f32x4 acc[8];
#pragma unroll
  for (int ni = 0; ni < 8; ++ni) acc[ni] = (f32x4){0.f, 0.f, 0.f, 0.f};
#pragma unroll
  for (int ks = 0; ks < 4; ++ks)
#pragma unroll
    for (int ni = 0; ni < 8; ++ni) {
      const bf16x8 bfr =
          *(const bf16x8*)&Bs[(ni * 16 + l15) * 136 + ks * 32 + quad * 8];
      acc[ni] = __builtin_amdgcn_mfma_f32_16x16x32_bf16(bfr, af[ks], acc[ni], 0, 0, 0);
    }

  // ---- epilogue 1: residual(bf16 global) + LN1; hLN1 -> regs + AF ----
  f32x4 hnew[8];
  {
    float s = 0.f, sq = 0.f;
#pragma unroll
    for (int ni = 0; ni < 8; ++ni) {
      const f32x4 bv = *(const f32x4*)(out_b + ni * 16 + quad * 4);
      const uint2 ru = *(const uint2*)(hb + grow * 128 + ni * 16 + quad * 4);
      const __hip_bfloat16* rh = (const __hip_bfloat16*)&ru;
#pragma unroll
      for (int r = 0; r < 4; ++r) {
        const float v = acc[ni][r] + bv[r] + __bfloat162float(rh[r]);
        hnew[ni][r] = v;
        s += v;
        sq += v * v;
      }
    }
    s += __shfl_xor(s, 16, 64);  sq += __shfl_xor(sq, 16, 64);
    s += __shfl_xor(s, 32, 64);  sq += __shfl_xor(sq, 32, 64);
    const float mean = s * (1.f / 128.f);
    const float var = sq * (1.f / 128.f) - mean * mean;
    const float rs = rsqrtf(var + 1e-5f);
#pragma unroll
    for (int ni = 0; ni < 8; ++ni) {
      const f32x4 g4 = *(const f32x4*)(ln1_g + ni * 16 + quad * 4);
      const f32x4 b4 = *(const f32x4*)(ln1_b + ni * 16 + quad * 4);
      f32x4 o;
#pragma unroll
      for (int r = 0; r < 4; ++r) o[r] = (hnew[ni][r] - mean) * rs * g4[r] + b4[r];
      hnew[ni] = o;
      *(uint2*)&AF[lrow * 136 + ni * 16 + quad * 4] =
          make_uint2(pk_rta(o[0], o[1]), pk_rta(o[2], o[3]));
    }
  }

  // FFN A-frags (reads own wave's AF writes — in-wave DS ordering)
  bf16x8 af2[4];
#pragma unroll
  for (int ks = 0; ks < 4; ++ks)
    af2[ks] = *(const bf16x8*)&AF[lrow * 136 + ks * 32 + quad * 8];

  // ---- FFN: acc = relu(hLN1@W1+b1)@W2, F chunks via AF ----
#pragma unroll
  for (int ni = 0; ni < 8; ++ni) acc[ni] = (f32x4){0.f, 0.f, 0.f, 0.f};

  for (int c = 0; c < 4; ++c) {
    __syncthreads();   // all waves done reading Bs (outw / W2_{c-1})
#pragma unroll
    for (int p = 0; p < 8; ++p) {
      const int e = tid + (p << 8);
      const int row = e >> 4, cc = e & 15;
      *(uint4*)&Bs[row * 136 + cc * 8] =
          *(const uint4*)(w1 + (size_t)(c * 128 + row) * 128 + cc * 8);
    }
    __syncthreads();

    // F chunk, transposed: row = n1-in-128 = ni*16+quad*4+r, col = node l15
    f32x4 fc[8];
#pragma unroll
    for (int ni = 0; ni < 8; ++ni) fc[ni] = (f32x4){0.f, 0.f, 0.f, 0.f};
#pragma unroll
    for (int ks = 0; ks < 4; ++ks)
#pragma unroll
      for (int ni = 0; ni < 8; ++ni) {
        const bf16x8 wf =
            *(const bf16x8*)&Bs[(ni * 16 + l15) * 136 + ks * 32 + quad * 8];
        fc[ni] = __builtin_amdgcn_mfma_f32_16x16x32_bf16(wf, af2[ks], fc[ni], 0, 0, 0);
      }
    // bias + relu + pack F into AF rows (wave-private)
#pragma unroll
    for (int ni = 0; ni < 8; ++ni) {
      const f32x4 bv = *(const f32x4*)(b1 + c * 128 + ni * 16 + quad * 4);
      const float v0 = fmaxf(fc[ni][0] + bv[0], 0.f);
      const float v1 = fmaxf(fc[ni][1] + bv[1], 0.f);
      const float v2 = fmaxf(fc[ni][2] + bv[2], 0.f);
      const float v3 = fmaxf(fc[ni][3] + bv[3], 0.f);
      *(uint2*)&AF[lrow * 136 + ni * 16 + quad * 4] =
          make_uint2(pk_rta(v0, v1), pk_rta(v2, v3));
    }
    __syncthreads();   // all waves done reading W1c from Bs
#pragma unroll
    for (int p = 0; p < 8; ++p) {
      const int e = tid + (p << 8);
      const int row = e >> 4, cc = e & 15;
      *(uint4*)&Bs[row * 136 + cc * 8] =
          *(const uint4*)(w2 + (size_t)row * 512 + c * 128 + cc * 8);
    }
    __syncthreads();

    // acc += (W2c, Fc): row = out-feature, col = node (F frags wave-private)
#pragma unroll
    for (int ks2 = 0; ks2 < 4; ++ks2) {
      const bf16x8 ff = *(const bf16x8*)&AF[lrow * 136 + ks2 * 32 + quad * 8];
#pragma unroll
      for (int ni = 0; ni < 8; ++ni) {
        const bf16x8 wf =
            *(const bf16x8*)&Bs[(ni * 16 + l15) * 136 + ks2 * 32 + quad * 8];
        acc[ni] = __builtin_amdgcn_mfma_f32_16x16x32_bf16(wf, ff, acc[ni], 0, 0, 0);
      }
    }
  }

  // ---- epilogue 2: residual (hnew, fp32 regs) + LN2 -> hb (uint2) ----
  {
    float s = 0.f, sq = 0.f;
#pragma unroll
    for (int ni = 0; ni < 8; ++ni) {
      const f32x4 bv = *(const f32x4*)(b2 + ni * 16 + quad * 4);
#pragma unroll
      for (int r = 0; r < 4; ++r) {
        const float v = acc[ni][r] + bv[r] + hnew[ni][r];
        acc[ni][r] = v;
        s += v;
        sq += v * v;
      }
    }
    s += __shfl_xor(s, 16, 64);  sq += __shfl_xor(sq, 16, 64);
    s += __shfl_xor(s, 32, 64);  sq += __shfl_xor(sq, 32, 64);
    const float mean = s * (1.f / 128.f);
    const float var = sq * (1.f / 128.f) - mean * mean;
    const float rs = rsqrtf(var + 1e-5f);
#pragma unroll
    for (int ni = 0; ni < 8; ++ni) {
      const f32x4 g4 = *(const f32x4*)(ln2_g + ni * 16 + quad * 4);
      const f32x4 b4 = *(const f32x4*)(ln2_b + ni * 16 + quad * 4);
      const float o0 = (acc[ni][0] - mean) * rs * g4[0] + b4[0];
      const float o1 = (acc[ni][1] - mean) * rs * g4[1] + b4[1];
      const float o2 = (acc[ni][2] - mean) * rs * g4[2] + b4[2];
      const float o3 = (acc[ni][3] - mean) * rs * g4[3] + b4[3];
      *(uint2*)(hb + grow * 128 + ni * 16 + quad * 4) =
          make_uint2(pk_rta(o0, o1), pk_rta(o2, o3));
    }
  }
}

// ---------------------------------------------------------------------------
// Fused QKV + flash attention, XCD-swizzled. Phase 1 now operand-swapped:
// Q,K = mfma(w, hf) -> row=dh, col=node: lane's 4 regs = 4 consecutive dh of
// one node -> uint2 store into PQ/Ks[node][dh..+3]. V = mfma(hf, wv) ->
// row=node, col=dh: 4 consecutive nodes?? no — row=node means regs = 4 nodes
// at fixed dh=l15 -> uint2 into Vt[dh][node..+3]. 12 ds_write_b64 vs 48
// scalar ds_write_u16 (kills measured bank conflicts). K-loop unchanged.
// ---------------------------------------------------------------------------
__global__ __launch_bounds__(512) void attn_kernel(
    const __hip_bfloat16* __restrict__ hbf,
    const __hip_bfloat16* __restrict__ qkvw_l,
    const float* __restrict__ qb_l,
    __hip_bfloat16* __restrict__ o)
{
  __shared__ __align__(16) __hip_bfloat16 Ks[512 * 24];
  __shared__ __align__(16) __hip_bfloat16 Vt[16 * 520];
  __shared__ __align__(16) __hip_bfloat16 PQ[8][1536];

  const int tid = threadIdx.x;
  const int b = blockIdx.x & 63;        // XCD-aware: graph in low bits
  const int hh = blockIdx.x >> 6;
  const __hip_bfloat16* hrow = hbf + (size_t)b * 512 * 128;

  const int wave = tid >> 6;
  const int lane = tid & 63;
  const int l31 = lane & 31;
  const int l5 = lane >> 5;
  const int l15 = lane & 15;
  const int quad = lane >> 4;
  const int q0 = wave * 64;

  // ---- phase 1: per-head QKV projection, packed-store epilogues ----
  {
    f32x4 qacc[4], kacc[4], vacc[4];
#pragma unroll
    for (int mt = 0; mt < 4; ++mt) {
      qacc[mt] = (f32x4){0.f, 0.f, 0.f, 0.f};
      kacc[mt] = (f32x4){0.f, 0.f, 0.f, 0.f};
      vacc[mt] = (f32x4){0.f, 0.f, 0.f, 0.f};
    }
#pragma unroll
    for (int ks = 0; ks < 4; ++ks) {
      const int kc = ks * 32 + quad * 8;
      const bf16x8 wq = *(const bf16x8*)(qkvw_l + (size_t)(hh * 16 + l15) * 128 + kc);
      const bf16x8 wk = *(const bf16x8*)(qkvw_l + (size_t)(128 + hh * 16 + l15) * 128 + kc);
      const bf16x8 wv = *(const bf16x8*)(qkvw_l + (size_t)(256 + hh * 16 + l15) * 128 + kc);
#pragma unroll
      for (int mt = 0; mt < 4; ++mt) {
        const bf16x8 hf =
            *(const bf16x8*)(hrow + (size_t)(q0 + mt * 16 + l15) * 128 + kc);
        // Q,K transposed: row = dh = quad*4+r, col = node = l15
        qacc[mt] = __builtin_amdgcn_mfma_f32_16x16x32_bf16(wq, hf, qacc[mt], 0, 0, 0);
        kacc[mt] = __builtin_amdgcn_mfma_f32_16x16x32_bf16(wk, hf, kacc[mt], 0, 0, 0);
        // V: row = node = quad*4+r, col = dh = l15
        vacc[mt] = __builtin_amdgcn_mfma_f32_16x16x32_bf16(hf, wv, vacc[mt], 0, 0, 0);
      }
    }
    const f32x4 qb4 = *(const f32x4*)(qb_l + hh * 16 + quad * 4);
    const f32x4 kb4 = *(const f32x4*)(qb_l + 128 + hh * 16 + quad * 4);
    const float vbs = qb_l[256 + hh * 16 + l15];
#pragma unroll
    for (int mt = 0; mt < 4; ++mt) {
      // PQ[node][dh..+3], Ks[node][dh..+3]: node = mt*16 + l15
      *(uint2*)&PQ[wave][(mt * 16 + l15) * 24 + quad * 4] =
          make_uint2(pk_rta(qacc[mt][0] + qb4[0], qacc[mt][1] + qb4[1]),
                     pk_rta(qacc[mt][2] + qb4[2], qacc[mt][3] + qb4[3]));
      *(uint2*)&Ks[(q0 + mt * 16 + l15) * 24 + quad * 4] =
          make_uint2(pk_rta(kacc[mt][0] + kb4[0], kacc[mt][1] + kb4[1]),
                     pk_rta(kacc[mt][2] + kb4[2], kacc[mt][3] + kb4[3]));
      // Vt[dh = l15][node = q0 + mt*16 + quad*4 + 0..3]
      *(uint2*)&Vt[l15 * 520 + q0 + mt * 16 + quad * 4] =
          make_uint2(pk_rta(vacc[mt][0] + vbs, vacc[mt][1] + vbs),
                     pk_rta(vacc[mt][2] + vbs, vacc[mt][3] + vbs));
    }
  }

  bf16x8 qf[2];
#pragma unroll
  for (int s = 0; s < 2; ++s)
    qf[s] = *(const bf16x8*)&PQ[wave][(s * 32 + l31) * 24 + l5 * 8];
  __syncthreads();

  // ---- phase 2: flash attention (unchanged) ----
  __hip_bfloat16* Pw = &PQ[wave][0];
  const f32x16 z16 = {};
  f32x4 oacc[2][2];
#pragma unroll
  for (int s = 0; s < 2; ++s) { oacc[s][0] = (f32x4){0.f,0.f,0.f,0.f};
                                oacc[s][1] = (f32x4){0.f,0.f,0.f,0.f}; }
  float lacc[2] = {0.f, 0.f};

  for (int kt = 0; kt < 16; ++kt) {
    const bf16x8 kf = *(const bf16x8*)&Ks[(kt * 32 + l31) * 24 + l5 * 8];
    const bf16x8 vf = *(const bf16x8*)&Vt[l15 * 520 + kt * 32 + quad * 8];
#pragma unroll
    for (int s = 0; s < 2; ++s) {
      f32x16 st = __builtin_amdgcn_mfma_f32_32x32x16_bf16(kf, qf[s], z16, 0, 0, 0);
      float pr[16];
#pragma unroll
      for (int r = 0; r < 16; ++r) pr[r] = FAST_EXP2(st[r]);
      const float s0 = (pr[0] + pr[1]) + (pr[2] + pr[3]);
      const float s1 = (pr[4] + pr[5]) + (pr[6] + pr[7]);
      const float s2 = (pr[8] + pr[9]) + (pr[10] + pr[11]);
      const float s3 = (pr[12] + pr[13]) + (pr[14] + pr[15]);
      lacc[s] += (s0 + s1) + (s2 + s3);
#pragma unroll
      for (int g = 0; g < 4; ++g) {
        *(uint2*)&Pw[l31 * 40 + g * 8 + l5 * 4] =
            make_uint2(pk_rta(pr[g * 4 + 0], pr[g * 4 + 1]),
                       pk_rta(pr[g * 4 + 2], pr[g * 4 + 3]));
      }
#pragma unroll
      for (int g = 0; g < 2; ++g) {
        const bf16x8 pf = *(const bf16x8*)&Pw[(g * 16 + l15) * 40 + quad * 8];
        oacc[s][g] = __builtin_amdgcn_mfma_f32_16x16x32_bf16(vf, pf, oacc[s][g], 0, 0, 0);
      }
    }
  }

#pragma unroll
  for (int s = 0; s < 2; ++s) {
    const float lv = lacc[s] + __shfl_xor(lacc[s], 32, 64);
#pragma unroll
    for (int g = 0; g < 2; ++g) {
      const float lq = __shfl(lv, g * 16 + l15, 64);
      const float inv = 1.f / lq;
      const int qrow = q0 + s * 32 + g * 16 + l15;
      *(uint2*)(o + ((size_t)b * 512 + qrow) * 128 + hh * 16 + quad * 4) =
          make_uint2(pk_rta(oacc[s][g][0] * inv, oacc[s][g][1] * inv),
                     pk_rta(oacc[s][g][2] * inv, oacc[s][g][3] * inv));
    }
  }
}

// ---------------------------------------------------------------------------
// Mean-pool (bf16 h) + 128->64 relu -> 64->10 head. One block per graph.
// ---------------------------------------------------------------------------
__global__ __launch_bounds__(256) void head_kernel(
    const __hip_bfloat16* __restrict__ h,
    const float* __restrict__ w1, const float* __restrict__ b1,
    const float* __restrict__ w2, const float* __restrict__ b2,
    float* __restrict__ out)
{
  __shared__ float part[2][128];
  __shared__ float pooled[128];
  __shared__ float hid[64];

  const int b = blockIdx.x;
  const int tid = threadIdx.x;
  const int d = tid & 127;
  const int half = tid >> 7;

  const __hip_bfloat16* hp = h + ((size_t)b * 512 + (size_t)half * 256) * 128;
  float s = 0.f;
  for (int r = 0; r < 256; ++r) s += __bfloat162float(hp[(size_t)r * 128 + d]);
  part[half][d] = s;
  __syncthreads();

  if (tid < 128) pooled[tid] = (part[0][tid] + part[1][tid]) * (1.f / 512.f);
  __syncthreads();

  if (tid < 64) {
    float a = b1[tid];
    for (int dd = 0; dd < 128; ++dd) a = fmaf(pooled[dd], w1[dd * 64 + tid], a);
    hid[tid] = fmaxf(a, 0.f);
  }
  __syncthreads();

  if (tid < 10) {
    float a = b2[tid];
    for (int j = 0; j < 64; ++j) a = fmaf(hid[j], w2[j * 10 + tid], a);
    out[b * 10 + tid] = a;
  }
}

// ---------------------------------------------------------------------------
extern "C" void kernel_launch(void* const* d_in, const int* in_sizes, int n_in,
                              void* d_out, int out_size, void* d_ws, size_t ws_size,
                              hipStream_t stream)
{
  (void)in_sizes; (void)n_in; (void)out_size; (void)ws_size;

  const float* x      = (const float*)d_in[0];
  const float* Wp     = (const float*)d_in[4];
  const float* bp     = (const float*)d_in[5];
  const float* qkv_w  = (const float*)d_in[6];
  const float* qkv_b  = (const float*)d_in[7];
  const float* out_w  = (const float*)d_in[8];
  const float* out_b  = (const float*)d_in[9];
  const float* ln1_g  = (const float*)d_in[10];
  const float* ln1_b  = (const float*)d_in[11];
  const float* ffn_w1 = (const float*)d_in[12];
  const float* ffn_b1 = (const float*)d_in[13];
  const float* ffn_w2 = (const float*)d_in[14];
  const float* ffn_b2 = (const float*)d_in[15];
  const float* ln2_g  = (const float*)d_in[16];
  const float* ln2_b  = (const float*)d_in[17];
  const float* cw1    = (const float*)d_in[18];
  const float* cb1    = (const float*)d_in[19];
  const float* cw2    = (const float*)d_in[20];
  const float* cb2    = (const float*)d_in[21];

  const int N = NROWS;

  // ws (bf16 activations): hbf | xb | attnb | weights | qb_s
  __hip_bfloat16* hbf   = (__hip_bfloat16*)d_ws;
  __hip_bfloat16* xb    = hbf + (size_t)N * 128;
  __hip_bfloat16* attnb = xb + (size_t)N * 128;
  __hip_bfloat16* wp_t  = attnb + (size_t)N * 128;
  __hip_bfloat16* qkvw  = wp_t + 128 * 128;
  __hip_bfloat16* outw  = qkvw + 6 * 384 * 128;
  __hip_bfloat16* w1t   = outw + 6 * 128 * 128;
  __hip_bfloat16* w2t   = w1t + 6 * 512 * 128;
  float* qb_s = (float*)(w2t + 6 * 128 * 512);

  const dim3 blk(256);

  // ---- single merged prep dispatch ----
  prep_kernel<<<dim3((PB7 + 255) / 256), blk, 0, stream>>>(
      x, xb, Wp, wp_t, qkv_w, qkvw, qkv_b, qb_s, out_w, outw,
      ffn_w1, w1t, ffn_w2, w2t);

  // ---- input projection: hbf = bf16(x @ Wp + bp) ----
  gemm_fk<<<dim3(N / 64), blk, 0, stream>>>(xb, wp_t, bp, hbf, N, 128);

  for (int i = 0; i < NLAYER; ++i) {
    // fused QKV + attention (XCD-swizzled grid, packed phase-1 stores)
    attn_kernel<<<dim3(64 * 8), dim3(512), 0, stream>>>(
        hbf, qkvw + (size_t)i * 384 * 128, qb_s + (size_t)i * 384, attnb);

    // hbf = LN2( LN1(hbf + attnb@outw^T+out_b) + FFN(...) ) — one kernel
    block_kernel<<<dim3(N / 64), blk, 0, stream>>>(
        attnb, hbf,
        outw + (size_t)i * 128 * 128, out_b + (size_t)i * 128,
        ln1_g + (size_t)i * 128, ln1_b + (size_t)i * 128,
        w1t + (size_t)i * 512 * 128, w2t + (size_t)i * 128 * 512,
        ffn_b1 + (size_t)i * 512, ffn_b2 + (size_t)i * 128,
        ln2_g + (size_t)i * 128, ln2_b + (size_t)i * 128);
  }

  head_kernel<<<dim3(64), blk, 0, stream>>>(hbf, cw1, cb1, cw2, cb2, (float*)d_out);
}

// Round 16
// 516.240 us; speedup vs baseline: 1.1625x; 1.1625x over previous
//
#include <hip/hip_runtime.h>
#include <hip/hip_bf16.h>

// Dense transformer forward, round 16 = R14 structure (separate gemm_fk
// outproj + ffn_fused — R15's merged block_kernel was latency-bound at 2
// resident blocks/CU with 17 exposed barriers and scattered epilogues) +
// R15's one good piece: attention phase-1 operand-swapped so Q/K/V epilogues
// are packed uint2 LDS stores (48 scalar ds_write_u16 -> 12 ds_write_b64).
// B=64 x L=512, D=128, H=8 (DH=16), LAYERS=6, FF=512, OUT=10. Mask all-true.

#define NROWS (64 * 512)
#define NLAYER 6

typedef __bf16 bf16x8 __attribute__((ext_vector_type(8)));
typedef float  f32x4  __attribute__((ext_vector_type(4)));
typedef float  f32x16 __attribute__((ext_vector_type(16)));

#define QSCALE 0.36067376022224085f   // 1/sqrt(16) * log2(e)

#if defined(__has_builtin)
#  if __has_builtin(__builtin_amdgcn_exp2f)
#    define FAST_EXP2(x) __builtin_amdgcn_exp2f(x)
#  endif
#endif
#ifndef FAST_EXP2
#  define FAST_EXP2(x) __expf((x) * 0.6931471805599453f)
#endif

__device__ __forceinline__ __hip_bfloat16 f2bf(float x) { return __float2bfloat16(x); }

__device__ __forceinline__ __hip_bfloat16 bf_rta(float a) {
  union { float f; unsigned u; } c{a};
  return __builtin_bit_cast(__hip_bfloat16, (unsigned short)((c.u + 0x8000u) >> 16));
}
__device__ __forceinline__ unsigned pk_rta(float a, float b) {
  union { float f; unsigned u; } ca{a}, cb{b};
  return ((ca.u + 0x8000u) >> 16) | ((cb.u + 0x8000u) & 0xFFFF0000u);
}

// ---------------------------------------------------------------------------
// Merged prep: x conversion + weight conversions/transposes + scaled qkv bias.
// ---------------------------------------------------------------------------
#define PN_X   (NROWS * 128)
#define PN_WP  (128 * 128)
#define PN_QW  (6 * 384 * 128)
#define PN_QB  (6 * 384)
#define PN_OW  (6 * 128 * 128)
#define PN_W1  (6 * 128 * 512)
#define PN_W2  (6 * 512 * 128)
#define PB1 PN_X
#define PB2 (PB1 + PN_WP)
#define PB3 (PB2 + PN_QW)
#define PB4 (PB3 + PN_QB)
#define PB5 (PB4 + PN_OW)
#define PB6 (PB5 + PN_W1)
#define PB7 (PB6 + PN_W2)

__global__ __launch_bounds__(256) void prep_kernel(
    const float* __restrict__ x, __hip_bfloat16* __restrict__ xb,
    const float* __restrict__ Wp, __hip_bfloat16* __restrict__ wp_t,
    const float* __restrict__ qkv_w, __hip_bfloat16* __restrict__ qkvw,
    const float* __restrict__ qkv_b, float* __restrict__ qb_s,
    const float* __restrict__ out_w, __hip_bfloat16* __restrict__ outw,
    const float* __restrict__ ffn_w1, __hip_bfloat16* __restrict__ w1t,
    const float* __restrict__ ffn_w2, __hip_bfloat16* __restrict__ w2t)
{
  const int idx = blockIdx.x * 256 + threadIdx.x;
  if (idx < PB1) {
    xb[idx] = f2bf(x[idx]);
  } else if (idx < PB2) {
    const int i = idx - PB1;
    const int c = i >> 7, r = i & 127;
    wp_t[i] = f2bf(Wp[r * 128 + c]);
  } else if (idx < PB3) {
    const int i = idx - PB2;
    const int row = (i >> 7) % 384;
    qkvw[i] = f2bf(qkv_w[i] * ((row < 128) ? QSCALE : 1.f));
  } else if (idx < PB4) {
    const int i = idx - PB3;
    qb_s[i] = qkv_b[i] * (((i % 384) < 128) ? QSCALE : 1.f);
  } else if (idx < PB5) {
    const int i = idx - PB4;
    outw[i] = f2bf(out_w[i]);
  } else if (idx < PB6) {
    const int i = idx - PB5;                 // [l][c][r], R=128, C=512
    const int l = i >> 16, j = i & 65535;
    const int c = j >> 7, r = j & 127;
    w1t[i] = f2bf(ffn_w1[l * 65536 + r * 512 + c]);
  } else if (idx < PB7) {
    const int i = idx - PB6;                 // [l][c][r], R=512, C=128
    const int l = i >> 16, j = i & 65535;
    const int c = j >> 9, r = j & 511;
    w2t[i] = f2bf(ffn_w2[l * 65536 + r * 128 + c]);
  }
}

// ---------------------------------------------------------------------------
// gemm_fk (R11/R13): Nn==128 GEMM, 64 rows/block (grid 512), full BK=128
// chunk staging -> 1 barrier pair per chunk (trailing elided). Wave owns 16
// full rows -> in-wave shfl LN. flags bit0 = relu; bit1 = fused residual+LN.
// ---------------------------------------------------------------------------
__global__ __launch_bounds__(256) void gemm_fk(
    const __hip_bfloat16* __restrict__ A, const __hip_bfloat16* __restrict__ B,
    const float* __restrict__ bias, __hip_bfloat16* __restrict__ outb,
    __hip_bfloat16* __restrict__ hb,
    const float* __restrict__ lng, const float* __restrict__ lnb,
    int M, int K, int flags)
{
  __shared__ __align__(16) __hip_bfloat16 As[64 * 136];
  __shared__ __align__(16) __hip_bfloat16 Bs[128 * 136];

  const int tid = threadIdx.x;
  const int m0 = blockIdx.x << 6;
  const int wave = tid >> 6;
  const int lane = tid & 63;
  const int quad = lane >> 4;
  const int l15 = lane & 15;
  const int wrow = wave * 16;

  f32x4 acc[8];
#pragma unroll
  for (int ni = 0; ni < 8; ++ni) acc[ni] = (f32x4){0.f, 0.f, 0.f, 0.f};

  for (int kc = 0; kc < K; kc += 128) {
#pragma unroll
    for (int p = 0; p < 4; ++p) {
      const int e = tid + (p << 8);
      const int row = e >> 4;
      const int c = e & 15;
      *(uint4*)&As[row * 136 + c * 8] =
          *(const uint4*)(A + (size_t)(m0 + row) * K + kc + c * 8);
    }
#pragma unroll
    for (int p = 0; p < 8; ++p) {
      const int e = tid + (p << 8);
      const int row = e >> 4;
      const int c = e & 15;
      *(uint4*)&Bs[row * 136 + c * 8] =
          *(const uint4*)(B + (size_t)row * K + kc + c * 8);
    }
    __syncthreads();

#pragma unroll
    for (int ks = 0; ks < 4; ++ks) {
      const bf16x8 af = *(const bf16x8*)&As[(wrow + l15) * 136 + ks * 32 + quad * 8];
#pragma unroll
      for (int ni = 0; ni < 8; ++ni) {
        const bf16x8 bfr =
            *(const bf16x8*)&Bs[(ni * 16 + l15) * 136 + ks * 32 + quad * 8];
        acc[ni] = __builtin_amdgcn_mfma_f32_16x16x32_bf16(af, bfr, acc[ni], 0, 0, 0);
      }
    }
    if (kc + 128 < K) __syncthreads();
  }

  if (flags & 2) {
#pragma unroll
    for (int r = 0; r < 4; ++r) {
      const size_t row = (size_t)(m0 + wrow + quad * 4 + r);
      float s = 0.f, sq = 0.f;
#pragma unroll
      for (int ni = 0; ni < 8; ++ni) {
        const int cl = ni * 16 + l15;
        const float v = acc[ni][r] + bias[cl] +
                        __bfloat162float(hb[row * 128 + cl]);
        acc[ni][r] = v;
        s += v;
        sq += v * v;
      }
#pragma unroll
      for (int off = 1; off <= 8; off <<= 1) {
        s += __shfl_xor(s, off, 64);
        sq += __shfl_xor(sq, off, 64);
      }
      const float mean = s * (1.f / 128.f);
      const float var = sq * (1.f / 128.f) - mean * mean;
      const float rs = rsqrtf(var + 1e-5f);
#pragma unroll
      for (int ni = 0; ni < 8; ++ni) {
        const int cl = ni * 16 + l15;
        const float o = (acc[ni][r] - mean) * rs * lng[cl] + lnb[cl];
        hb[row * 128 + cl] = bf_rta(o);
      }
    }
  } else {
#pragma unroll
    for (int ni = 0; ni < 8; ++ni) {
      const int cl = ni * 16 + l15;
      const float bv = bias[cl];
#pragma unroll
      for (int r = 0; r < 4; ++r) {
        float v = acc[ni][r] + bv;
        if (flags & 1) v = fmaxf(v, 0.f);
        outb[(size_t)(m0 + wrow + quad * 4 + r) * 128 + cl] = bf_rta(v);
      }
    }
  }
}

// ---------------------------------------------------------------------------
// Fused FFN (R14): hb = LN(hb + relu(hb@W1 + b1)@W2 + b2), ff stays in LDS.
// ---------------------------------------------------------------------------
__global__ __launch_bounds__(256) void ffn_fused(
    __hip_bfloat16* __restrict__ hb,
    const __hip_bfloat16* __restrict__ w1,   // layer [512 n][128 k] bf16
    const __hip_bfloat16* __restrict__ w2,   // layer [128 n][512 k] bf16
    const float* __restrict__ b1, const float* __restrict__ b2,
    const float* __restrict__ lng, const float* __restrict__ lnb)
{
  __shared__ __align__(16) __hip_bfloat16 AF[64 * 136];   // A tile, then F
  __shared__ __align__(16) __hip_bfloat16 Bs[128 * 136];  // W1c / W2c

  const int tid = threadIdx.x;
  const int m0 = blockIdx.x << 6;
  const int wave = tid >> 6;
  const int lane = tid & 63;
  const int quad = lane >> 4;
  const int l15 = lane & 15;
  const int wrow = wave * 16;

#pragma unroll
  for (int p = 0; p < 4; ++p) {
    const int e = tid + (p << 8);
    const int row = e >> 4, c = e & 15;
    *(uint4*)&AF[row * 136 + c * 8] =
        *(const uint4*)(hb + (size_t)(m0 + row) * 128 + c * 8);
  }
#pragma unroll
  for (int p = 0; p < 8; ++p) {
    const int e = tid + (p << 8);
    const int row = e >> 4, c = e & 15;
    *(uint4*)&Bs[row * 136 + c * 8] =
        *(const uint4*)(w1 + (size_t)row * 128 + c * 8);
  }
  __syncthreads();

  bf16x8 af[4];
#pragma unroll
  for (int ks = 0; ks < 4; ++ks)
    af[ks] = *(const bf16x8*)&AF[(wrow + l15) * 136 + ks * 32 + quad * 8];

  f32x4 oacc[8];
#pragma unroll
  for (int ni = 0; ni < 8; ++ni) oacc[ni] = (f32x4){0.f, 0.f, 0.f, 0.f};

  for (int c = 0; c < 4; ++c) {
    if (c > 0) {
      __syncthreads();
#pragma unroll
      for (int p = 0; p < 8; ++p) {
        const int e = tid + (p << 8);
        const int row = e >> 4, cc = e & 15;
        *(uint4*)&Bs[row * 136 + cc * 8] =
            *(const uint4*)(w1 + (size_t)(c * 128 + row) * 128 + cc * 8);
      }
      __syncthreads();
    }

    f32x4 fc[8];
#pragma unroll
    for (int ni = 0; ni < 8; ++ni) fc[ni] = (f32x4){0.f, 0.f, 0.f, 0.f};
#pragma unroll
    for (int ks = 0; ks < 4; ++ks)
#pragma unroll
      for (int ni = 0; ni < 8; ++ni) {
        const bf16x8 wf =
            *(const bf16x8*)&Bs[(ni * 16 + l15) * 136 + ks * 32 + quad * 8];
        fc[ni] = __builtin_amdgcn_mfma_f32_16x16x32_bf16(wf, af[ks], fc[ni], 0, 0, 0);
      }
#pragma unroll
    for (int ni = 0; ni < 8; ++ni) {
      const f32x4 bv = *(const f32x4*)(b1 + c * 128 + ni * 16 + quad * 4);
      const float v0 = fmaxf(fc[ni][0] + bv[0], 0.f);
      const float v1 = fmaxf(fc[ni][1] + bv[1], 0.f);
      const float v2 = fmaxf(fc[ni][2] + bv[2], 0.f);
      const float v3 = fmaxf(fc[ni][3] + bv[3], 0.f);
      *(uint2*)&AF[(wrow + l15) * 136 + ni * 16 + quad * 4] =
          make_uint2(pk_rta(v0, v1), pk_rta(v2, v3));
    }
    __syncthreads();

#pragma unroll
    for (int p = 0; p < 8; ++p) {
      const int e = tid + (p << 8);
      const int row = e >> 4, cc = e & 15;
      *(uint4*)&Bs[row * 136 + cc * 8] =
          *(const uint4*)(w2 + (size_t)row * 512 + c * 128 + cc * 8);
    }
    __syncthreads();

#pragma unroll
    for (int ks2 = 0; ks2 < 4; ++ks2) {
      const bf16x8 ff =
          *(const bf16x8*)&AF[(wrow + l15) * 136 + ks2 * 32 + quad * 8];
#pragma unroll
      for (int ni = 0; ni < 8; ++ni) {
        const bf16x8 wf =
            *(const bf16x8*)&Bs[(ni * 16 + l15) * 136 + ks2 * 32 + quad * 8];
        oacc[ni] = __builtin_amdgcn_mfma_f32_16x16x32_bf16(ff, wf, oacc[ni], 0, 0, 0);
      }
    }
  }

#pragma unroll
  for (int r = 0; r < 4; ++r) {
    const size_t row = (size_t)(m0 + wrow + quad * 4 + r);
    float s = 0.f, sq = 0.f;
#pragma unroll
    for (int ni = 0; ni < 8; ++ni) {
      const int cl = ni * 16 + l15;
      const float v = oacc[ni][r] + b2[cl] + __bfloat162float(hb[row * 128 + cl]);
      oacc[ni][r] = v;
      s += v;
      sq += v * v;
    }
#pragma unroll
    for (int off = 1; off <= 8; off <<= 1) {
      s += __shfl_xor(s, off, 64);
      sq += __shfl_xor(sq, off, 64);
    }
    const float mean = s * (1.f / 128.f);
    const float var = sq * (1.f / 128.f) - mean * mean;
    const float rs = rsqrtf(var + 1e-5f);
#pragma unroll
    for (int ni = 0; ni < 8; ++ni) {
      const int cl = ni * 16 + l15;
      const float o = (oacc[ni][r] - mean) * rs * lng[cl] + lnb[cl];
      hb[row * 128 + cl] = bf_rta(o);
    }
  }
}

// ---------------------------------------------------------------------------
// Fused QKV + flash attention, XCD-swizzled; phase-1 operand-swapped with
// packed uint2 LDS stores (R15's verified change). K-loop unchanged.
// ---------------------------------------------------------------------------
__global__ __launch_bounds__(512) void attn_kernel(
    const __hip_bfloat16* __restrict__ hbf,
    const __hip_bfloat16* __restrict__ qkvw_l,
    const float* __restrict__ qb_l,
    __hip_bfloat16* __restrict__ o)
{
  __shared__ __align__(16) __hip_bfloat16 Ks[512 * 24];
  __shared__ __align__(16) __hip_bfloat16 Vt[16 * 520];
  __shared__ __align__(16) __hip_bfloat16 PQ[8][1536];

  const int tid = threadIdx.x;
  const int b = blockIdx.x & 63;        // XCD-aware: graph in low bits
  const int hh = blockIdx.x >> 6;
  const __hip_bfloat16* hrow = hbf + (size_t)b * 512 * 128;

  const int wave = tid >> 6;
  const int lane = tid & 63;
  const int l31 = lane & 31;
  const int l5 = lane >> 5;
  const int l15 = lane & 15;
  const int quad = lane >> 4;
  const int q0 = wave * 64;

  // ---- phase 1: per-head QKV projection, packed-store epilogues ----
  {
    f32x4 qacc[4], kacc[4], vacc[4];
#pragma unroll
    for (int mt = 0; mt < 4; ++mt) {
      qacc[mt] = (f32x4){0.f, 0.f, 0.f, 0.f};
      kacc[mt] = (f32x4){0.f, 0.f, 0.f, 0.f};
      vacc[mt] = (f32x4){0.f, 0.f, 0.f, 0.f};
    }
#pragma unroll
    for (int ks = 0; ks < 4; ++ks) {
      const int kc = ks * 32 + quad * 8;
      const bf16x8 wq = *(const bf16x8*)(qkvw_l + (size_t)(hh * 16 + l15) * 128 + kc);
      const bf16x8 wk = *(const bf16x8*)(qkvw_l + (size_t)(128 + hh * 16 + l15) * 128 + kc);
      const bf16x8 wv = *(const bf16x8*)(qkvw_l + (size_t)(256 + hh * 16 + l15) * 128 + kc);
#pragma unroll
      for (int mt = 0; mt < 4; ++mt) {
        const bf16x8 hf =
            *(const bf16x8*)(hrow + (size_t)(q0 + mt * 16 + l15) * 128 + kc);
        // Q,K transposed: row = dh = quad*4+r, col = node = l15
        qacc[mt] = __builtin_amdgcn_mfma_f32_16x16x32_bf16(wq, hf, qacc[mt], 0, 0, 0);
        kacc[mt] = __builtin_amdgcn_mfma_f32_16x16x32_bf16(wk, hf, kacc[mt], 0, 0, 0);
        // V: row = node = quad*4+r, col = dh = l15
        vacc[mt] = __builtin_amdgcn_mfma_f32_16x16x32_bf16(hf, wv, vacc[mt], 0, 0, 0);
      }
    }
    const f32x4 qb4 = *(const f32x4*)(qb_l + hh * 16 + quad * 4);
    const f32x4 kb4 = *(const f32x4*)(qb_l + 128 + hh * 16 + quad * 4);
    const float vbs = qb_l[256 + hh * 16 + l15];
#pragma unroll
    for (int mt = 0; mt < 4; ++mt) {
      // PQ[node][dh..+3], Ks[node][dh..+3]: node = mt*16 + l15 (Q wave-local)
      *(uint2*)&PQ[wave][(mt * 16 + l15) * 24 + quad * 4] =
          make_uint2(pk_rta(qacc[mt][0] + qb4[0], qacc[mt][1] + qb4[1]),
                     pk_rta(qacc[mt][2] + qb4[2], qacc[mt][3] + qb4[3]));
      *(uint2*)&Ks[(q0 + mt * 16 + l15) * 24 + quad * 4] =
          make_uint2(pk_rta(kacc[mt][0] + kb4[0], kacc[mt][1] + kb4[1]),
                     pk_rta(kacc[mt][2] + kb4[2], kacc[mt][3] + kb4[3]));
      // Vt[dh = l15][node = q0 + mt*16 + quad*4 + 0..3]
      *(uint2*)&Vt[l15 * 520 + q0 + mt * 16 + quad * 4] =
          make_uint2(pk_rta(vacc[mt][0] + vbs, vacc[mt][1] + vbs),
                     pk_rta(vacc[mt][2] + vbs, vacc[mt][3] + vbs));
    }
  }

  bf16x8 qf[2];
#pragma unroll
  for (int s = 0; s < 2; ++s)
    qf[s] = *(const bf16x8*)&PQ[wave][(s * 32 + l31) * 24 + l5 * 8];
  __syncthreads();

  // ---- phase 2: flash attention ----
  __hip_bfloat16* Pw = &PQ[wave][0];
  const f32x16 z16 = {};
  f32x4 oacc[2][2];
#pragma unroll
  for (int s = 0; s < 2; ++s) { oacc[s][0] = (f32x4){0.f,0.f,0.f,0.f};
                                oacc[s][1] = (f32x4){0.f,0.f,0.f,0.f}; }
  float lacc[2] = {0.f, 0.f};

  for (int kt = 0; kt < 16; ++kt) {
    const bf16x8 kf = *(const bf16x8*)&Ks[(kt * 32 + l31) * 24 + l5 * 8];
    const bf16x8 vf = *(const bf16x8*)&Vt[l15 * 520 + kt * 32 + quad * 8];
#pragma unroll
    for (int s = 0; s < 2; ++s) {
      f32x16 st = __builtin_amdgcn_mfma_f32_32x32x16_bf16(kf, qf[s], z16, 0, 0, 0);
      float pr[16];
#pragma unroll
      for (int r = 0; r < 16; ++r) pr[r] = FAST_EXP2(st[r]);
      const float s0 = (pr[0] + pr[1]) + (pr[2] + pr[3]);
      const float s1 = (pr[4] + pr[5]) + (pr[6] + pr[7]);
      const float s2 = (pr[8] + pr[9]) + (pr[10] + pr[11]);
      const float s3 = (pr[12] + pr[13]) + (pr[14] + pr[15]);
      lacc[s] += (s0 + s1) + (s2 + s3);
#pragma unroll
      for (int g = 0; g < 4; ++g) {
        *(uint2*)&Pw[l31 * 40 + g * 8 + l5 * 4] =
            make_uint2(pk_rta(pr[g * 4 + 0], pr[g * 4 + 1]),
                       pk_rta(pr[g * 4 + 2], pr[g * 4 + 3]));
      }
#pragma unroll
      for (int g = 0; g < 2; ++g) {
        const bf16x8 pf = *(const bf16x8*)&Pw[(g * 16 + l15) * 40 + quad * 8];
        oacc[s][g] = __builtin_amdgcn_mfma_f32_16x16x32_bf16(vf, pf, oacc[s][g], 0, 0, 0);
      }
    }
  }

#pragma unroll
  for (int s = 0; s < 2; ++s) {
    const float lv = lacc[s] + __shfl_xor(lacc[s], 32, 64);
#pragma unroll
    for (int g = 0; g < 2; ++g) {
      const float lq = __shfl(lv, g * 16 + l15, 64);
      const float inv = 1.f / lq;
      const int qrow = q0 + s * 32 + g * 16 + l15;
      *(uint2*)(o + ((size_t)b * 512 + qrow) * 128 + hh * 16 + quad * 4) =
          make_uint2(pk_rta(oacc[s][g][0] * inv, oacc[s][g][1] * inv),
                     pk_rta(oacc[s][g][2] * inv, oacc[s][g][3] * inv));
    }
  }
}

// ---------------------------------------------------------------------------
// Mean-pool (bf16 h) + 128->64 relu -> 64->10 head. One block per graph.
// ---------------------------------------------------------------------------
__global__ __launch_bounds__(256) void head_kernel(
    const __hip_bfloat16* __restrict__ h,
    const float* __restrict__ w1, const float* __restrict__ b1,
    const float* __restrict__ w2, const float* __restrict__ b2,
    float* __restrict__ out)
{
  __shared__ float part[2][128];
  __shared__ float pooled[128];
  __shared__ float hid[64];

  const int b = blockIdx.x;
  const int tid = threadIdx.x;
  const int d = tid & 127;
  const int half = tid >> 7;

  const __hip_bfloat16* hp = h + ((size_t)b * 512 + (size_t)half * 256) * 128;
  float s = 0.f;
  for (int r = 0; r < 256; ++r) s += __bfloat162float(hp[(size_t)r * 128 + d]);
  part[half][d] = s;
  __syncthreads();

  if (tid < 128) pooled[tid] = (part[0][tid] + part[1][tid]) * (1.f / 512.f);
  __syncthreads();

  if (tid < 64) {
    float a = b1[tid];
    for (int dd = 0; dd < 128; ++dd) a = fmaf(pooled[dd], w1[dd * 64 + tid], a);
    hid[tid] = fmaxf(a, 0.f);
  }
  __syncthreads();

  if (tid < 10) {
    float a = b2[tid];
    for (int j = 0; j < 64; ++j) a = fmaf(hid[j], w2[j * 10 + tid], a);
    out[b * 10 + tid] = a;
  }
}

// ---------------------------------------------------------------------------
extern "C" void kernel_launch(void* const* d_in, const int* in_sizes, int n_in,
                              void* d_out, int out_size, void* d_ws, size_t ws_size,
                              hipStream_t stream)
{
  (void)in_sizes; (void)n_in; (void)out_size; (void)ws_size;

  const float* x      = (const float*)d_in[0];
  const float* Wp     = (const float*)d_in[4];
  const float* bp     = (const float*)d_in[5];
  const float* qkv_w  = (const float*)d_in[6];
  const float* qkv_b  = (const float*)d_in[7];
  const float* out_w  = (const float*)d_in[8];
  const float* out_b  = (const float*)d_in[9];
  const float* ln1_g  = (const float*)d_in[10];
  const float* ln1_b  = (const float*)d_in[11];
  const float* ffn_w1 = (const float*)d_in[12];
  const float* ffn_b1 = (const float*)d_in[13];
  const float* ffn_w2 = (const float*)d_in[14];
  const float* ffn_b2 = (const float*)d_in[15];
  const float* ln2_g  = (const float*)d_in[16];
  const float* ln2_b  = (const float*)d_in[17];
  const float* cw1    = (const float*)d_in[18];
  const float* cb1    = (const float*)d_in[19];
  const float* cw2    = (const float*)d_in[20];
  const float* cb2    = (const float*)d_in[21];

  const int N = NROWS;

  // ws (bf16 activations): hbf | xb | attnb | weights | qb_s
  __hip_bfloat16* hbf   = (__hip_bfloat16*)d_ws;
  __hip_bfloat16* xb    = hbf + (size_t)N * 128;
  __hip_bfloat16* attnb = xb + (size_t)N * 128;
  __hip_bfloat16* wp_t  = attnb + (size_t)N * 128;
  __hip_bfloat16* qkvw  = wp_t + 128 * 128;
  __hip_bfloat16* outw  = qkvw + 6 * 384 * 128;
  __hip_bfloat16* w1t   = outw + 6 * 128 * 128;
  __hip_bfloat16* w2t   = w1t + 6 * 512 * 128;
  float* qb_s = (float*)(w2t + 6 * 128 * 512);

  const dim3 blk(256);
  __hip_bfloat16* const nob = (__hip_bfloat16*)nullptr;
  const float* const nof = (const float*)nullptr;

  // ---- single merged prep dispatch ----
  prep_kernel<<<dim3((PB7 + 255) / 256), blk, 0, stream>>>(
      x, xb, Wp, wp_t, qkv_w, qkvw, qkv_b, qb_s, out_w, outw,
      ffn_w1, w1t, ffn_w2, w2t);

  // ---- input projection: hbf = bf16(x @ Wp + bp) ----
  gemm_fk<<<dim3(N / 64), blk, 0, stream>>>(
      xb, wp_t, bp, hbf, nob, nof, nof, N, 128, 0);

  for (int i = 0; i < NLAYER; ++i) {
    // fused QKV + attention (XCD-swizzled grid, packed phase-1 stores)
    attn_kernel<<<dim3(64 * 8), dim3(512), 0, stream>>>(
        hbf, qkvw + (size_t)i * 384 * 128, qb_s + (size_t)i * 384, attnb);

    // hbf = LN(hbf + attnb @ out_w^T + out_b)
    gemm_fk<<<dim3(N / 64), blk, 0, stream>>>(
        attnb, outw + (size_t)i * 128 * 128, out_b + (size_t)i * 128,
        nob, hbf, ln1_g + (size_t)i * 128, ln1_b + (size_t)i * 128,
        N, 128, 2);

    // hbf = LN(hbf + relu(hbf@W1 + b1)@W2 + b2) — ff stays in LDS
    ffn_fused<<<dim3(N / 64), blk, 0, stream>>>(
        hbf, w1t + (size_t)i * 512 * 128, w2t + (size_t)i * 128 * 512,
        ffn_b1 + (size_t)i * 512, ffn_b2 + (size_t)i * 128,
        ln2_g + (size_t)i * 128, ln2_b + (size_t)i * 128);
  }

  head_kernel<<<dim3(64), blk, 0, stream>>>(hbf, cw1, cb1, cw2, cb2, (float*)d_out);
}